// Round 1
// baseline (415.218 us; speedup 1.0000x reference)
//
#include <hip/hip_runtime.h>
#include <hip/hip_bf16.h>
#include <math.h>

// Problem dims
#define BBATCH 128
#define NCHAN  22
#define TLEN   1000
#define F1C    8
#define F2C    16
#define L1W    31
#define L2W    38
#define LSEQ   69
#define EDIM   16
#define NHEAD  8
#define FFDIM  64

// const block offsets (in floats, within ws)
#define C_SA   0
#define C_BA   16
#define C_BC2  32
#define C_W2F  48
#define C_TOTAL (48 + 16*22*30)

// ws layout (floats)
#define OFF_CONST 0
#define OFF_BUFA  16384
#define OFF_BUFB  (OFF_BUFA + 2048000)
#define OFF_SEQ   (OFF_BUFB + 2048000)
#define OFF_HBUF  (OFF_SEQ + 141312)
// qkv and obuf alias bufA (dead after pool1)
#define OFF_QKV   OFF_BUFA
#define OFF_OBUF  (OFF_BUFA + 423936)

// ---------------- setup: fold BN + compose branch-2 filter ----------------
__global__ void k_setup(const float* __restrict__ wsp1a, const float* __restrict__ b_spec1,
                        const float* __restrict__ g_bn1, const float* __restrict__ b_bn1,
                        const float* __restrict__ g_bn3, const float* __restrict__ b_bn3,
                        const float* __restrict__ w_spec2, const float* __restrict__ b_spec2,
                        const float* __restrict__ g_bn2, const float* __restrict__ b_bn2,
                        const float* __restrict__ w_sp2, const float* __restrict__ b_sp2,
                        const float* __restrict__ g_bn5, const float* __restrict__ b_bn5,
                        float* __restrict__ consts)
{
    int tid = threadIdx.x;
    float rbn = rsqrtf(1.0f + 1e-5f);
    if (tid < 16) {
        int c2 = tid, c1 = c2 >> 1;
        float wsum = 0.f;
        for (int h = 0; h < NCHAN; h++) wsum += wsp1a[c2*NCHAN + h];
        float s1b = g_bn1[c1] * rbn;
        float s3  = g_bn3[c2] * rbn;
        float C1  = (s1b * b_spec1[c1] + b_bn1[c1]) * wsum;
        consts[C_SA + c2] = s3 * s1b;
        consts[C_BA + c2] = s3 * C1 + b_bn3[c2];
        // branch-2 bias
        float s5 = g_bn5[c2] * rbn;
        float acc = b_sp2[c2];
        for (int cc = 0; cc < F1C; cc++) {
            float s2b = g_bn2[cc] * rbn;
            float cb  = s2b * b_spec2[cc] + b_bn2[cc];
            float wsh = 0.f;
            for (int h = 0; h < NCHAN; h++) wsh += w_sp2[(c2*F1C + cc)*NCHAN + h];
            acc += wsh * cb;
        }
        consts[C_BC2 + c2] = s5 * acc + b_bn5[c2];
    }
    for (int idx = tid; idx < 16*22*30; idx += 256) {
        int c2 = idx / 660;
        int rem = idx % 660;
        int h = rem / 30, k = rem % 30;
        float s5 = g_bn5[c2] * rbn;
        float s = 0.f;
        for (int cc = 0; cc < F1C; cc++)
            s += w_sp2[(c2*F1C + cc)*NCHAN + h] * (g_bn2[cc] * rbn) * w_spec2[cc*30 + k];
        consts[C_W2F + idx] = s5 * s;
    }
}

// ---------------- branch 1: h-mixing first (linearity swap) ----------------
__global__ void k_mix1(const float* __restrict__ x, const float* __restrict__ wsp1a,
                       float* __restrict__ u1)
{
    int bid = blockIdx.x;           // b*16 + c2
    int c2 = bid & 15, b = bid >> 4;
    float wl[NCHAN];
#pragma unroll
    for (int h = 0; h < NCHAN; h++) wl[h] = wsp1a[c2*NCHAN + h];
    const float* xb = x + b * NCHAN * TLEN;
    float* ub = u1 + bid * TLEN;
    for (int t = threadIdx.x; t < TLEN; t += 256) {
        float s = 0.f;
#pragma unroll
        for (int h = 0; h < NCHAN; h++) s += wl[h] * xb[h*TLEN + t];
        ub[t] = s;
    }
}

// 125-tap temporal conv + bn1/bn3-folded affine + ELU
__global__ void k_conv125(const float* __restrict__ u1, const float* __restrict__ w_spec1,
                          const float* __restrict__ consts, float* __restrict__ e1)
{
    __shared__ float row[TLEN + 124];
    __shared__ float wk[125];
    int bid = blockIdx.x;           // b*16 + c2
    int c2 = bid & 15;
    int c1 = c2 >> 1;
    const float* ub = u1 + bid * TLEN;
    for (int i = threadIdx.x; i < TLEN + 124; i += 256) {
        int t = i - 62;
        row[i] = (t >= 0 && t < TLEN) ? ub[t] : 0.f;
    }
    for (int i = threadIdx.x; i < 125; i += 256) wk[i] = w_spec1[c1*125 + i];
    float sa = consts[C_SA + c2], ba = consts[C_BA + c2];
    __syncthreads();
    for (int t = threadIdx.x; t < TLEN; t += 256) {
        float s = 0.f;
#pragma unroll
        for (int k = 0; k < 125; k++) s += wk[k] * row[t + k];
        float a = sa * s + ba;
        e1[bid*TLEN + t] = (a > 0.f) ? a : (expf(a) - 1.f);
    }
}

// pointwise 16x16 conv + bn4 + ELU
__global__ void k_pw(const float* __restrict__ e1, const float* __restrict__ w_sp1b,
                     const float* __restrict__ b_sp1b, const float* __restrict__ g_bn4,
                     const float* __restrict__ b_bn4, float* __restrict__ g1out)
{
    __shared__ float wb[256];
    __shared__ float sb[16], bb[16];
    int tid = threadIdx.x;
    wb[tid] = w_sp1b[tid];
    if (tid < 16) {
        float rbn = rsqrtf(1.0f + 1e-5f);
        float s = g_bn4[tid] * rbn;
        sb[tid] = s;
        bb[tid] = s * b_sp1b[tid] + b_bn4[tid];
    }
    __syncthreads();
    int idx = blockIdx.x * 256 + tid;   // over (b,t): 128*1000
    if (idx >= BBATCH * TLEN) return;
    int t = idx % TLEN, b = idx / TLEN;
    float ev[16];
#pragma unroll
    for (int j = 0; j < 16; j++) ev[j] = e1[(b*16 + j)*TLEN + t];
#pragma unroll
    for (int c = 0; c < 16; c++) {
        float s = 0.f;
#pragma unroll
        for (int j = 0; j < 16; j++) s += wb[c*16 + j] * ev[j];
        float a = sb[c] * s + bb[c];
        g1out[(b*16 + c)*TLEN + t] = (a > 0.f) ? a : (expf(a) - 1.f);
    }
}

// avgpool 32/32 -> seq[:, 0:31, :]
__global__ void k_pool1(const float* __restrict__ g1, float* __restrict__ seq)
{
    int idx = blockIdx.x * 256 + threadIdx.x;   // 128*16*31
    if (idx >= BBATCH * 16 * L1W) return;
    int tw = idx % L1W;
    int c2 = (idx / L1W) & 15;
    int b = idx / (16 * L1W);
    const float* g = g1 + (b*16 + c2)*TLEN + 32*tw;
    float s = 0.f;
#pragma unroll
    for (int i = 0; i < 32; i++) s += g[i];
    seq[(b*LSEQ + tw)*16 + c2] = s * (1.f/32.f);
}

// ---------------- branch 2: single fused conv (16,22,30) + square ----------
__global__ void k_b2conv(const float* __restrict__ x, const float* __restrict__ consts,
                         float* __restrict__ v2)
{
    __shared__ float row[TLEN + 30];
    __shared__ float wf[660];
    int bid = blockIdx.x;           // b*16 + c2
    int c2 = bid & 15, b = bid >> 4;
    for (int i = threadIdx.x; i < 660; i += 256) wf[i] = consts[C_W2F + c2*660 + i];
    float acc[4] = {0.f, 0.f, 0.f, 0.f};
    const float* xb = x + b * NCHAN * TLEN;
    for (int h = 0; h < NCHAN; h++) {
        __syncthreads();
        for (int i = threadIdx.x; i < TLEN + 30; i += 256) {
            int t = i - 14;
            row[i] = (t >= 0 && t < TLEN) ? xb[h*TLEN + t] : 0.f;
        }
        __syncthreads();
        const float* wh = &wf[h*30];
#pragma unroll
        for (int it = 0; it < 4; it++) {
            int t = threadIdx.x + it*256;
            if (t < TLEN) {
                float s = 0.f;
#pragma unroll
                for (int k = 0; k < 30; k++) s += wh[k] * row[t + k];
                acc[it] += s;
            }
        }
    }
    float bc = consts[C_BC2 + c2];
#pragma unroll
    for (int it = 0; it < 4; it++) {
        int t = threadIdx.x + it*256;
        if (t < TLEN) {
            float a = acc[it] + bc;
            v2[bid*TLEN + t] = a * a;
        }
    }
}

// avgpool 75/25 + log(clip) -> seq[:, 31:69, :]
__global__ void k_pool2(const float* __restrict__ v2, float* __restrict__ seq)
{
    int idx = blockIdx.x * 256 + threadIdx.x;   // 128*16*38
    if (idx >= BBATCH * 16 * L2W) return;
    int tw = idx % L2W;
    int c2 = (idx / L2W) & 15;
    int b = idx / (16 * L2W);
    const float* v = v2 + (b*16 + c2)*TLEN + 25*tw;
    float s = 0.f;
    for (int i = 0; i < 75; i++) s += v[i];
    float m = s * (1.f/75.f);
    seq[(b*LSEQ + 31 + tw)*16 + c2] = logf(fmaxf(m, 1e-6f));
}

// ---------------- linear SSM scan ----------------
__global__ void k_ssm(const float* __restrict__ seq, const float* __restrict__ Amat,
                      const float* __restrict__ Bmat, const float* __restrict__ Cmat,
                      float* __restrict__ hbuf)
{
    __shared__ float Al[256], Bl[256], Cl[256];
    __shared__ float st[16][17], xt[16][17];
    int tid = threadIdx.x;
    Al[tid] = Amat[tid]; Bl[tid] = Bmat[tid]; Cl[tid] = Cmat[tid];
    int bb = tid >> 4, j = tid & 15;
    int b = blockIdx.x * 16 + bb;
    st[bb][j] = 0.f;
    __syncthreads();
    for (int l = 0; l < LSEQ; l++) {
        xt[bb][j] = seq[(b*LSEQ + l)*16 + j];
        __syncthreads();
        float nv = 0.f;
#pragma unroll
        for (int i = 0; i < 16; i++)
            nv += st[bb][i]*Al[i*16 + j] + xt[bb][i]*Bl[j*16 + i];
        __syncthreads();
        st[bb][j] = nv;
        __syncthreads();
        float ov = 0.f;
#pragma unroll
        for (int i = 0; i < 16; i++) ov += st[bb][i]*Cl[j*16 + i];
        hbuf[(b*LSEQ + l)*16 + j] = ov;
    }
}

// ---------------- transformer: qkv projection ----------------
__global__ void k_qkv(const float* __restrict__ h, const float* __restrict__ qkvw,
                      const float* __restrict__ qkvb, float* __restrict__ qkv)
{
    __shared__ float wl[768];
    __shared__ float bl[48];
    int tid = threadIdx.x;
    for (int i = tid; i < 768; i += 256) wl[i] = qkvw[i];
    if (tid < 48) bl[tid] = qkvb[tid];
    __syncthreads();
    int r = blockIdx.x * 256 + tid;
    if (r >= BBATCH * LSEQ) return;
    float hv[16];
    const float4* hp = (const float4*)(h + r*16);
#pragma unroll
    for (int i = 0; i < 4; i++) {
        float4 a = hp[i];
        hv[4*i] = a.x; hv[4*i+1] = a.y; hv[4*i+2] = a.z; hv[4*i+3] = a.w;
    }
#pragma unroll
    for (int o = 0; o < 48; o++) {
        float s = bl[o];
#pragma unroll
        for (int c = 0; c < 16; c++) s += wl[o*16 + c] * hv[c];
        qkv[r*48 + o] = s;
    }
}

// attention over the batch axis: per (n, head), S=T=128, hd=2
__global__ void k_attn(const float* __restrict__ qkv, float* __restrict__ obuf)
{
    int n = blockIdx.x >> 3, hh = blockIdx.x & 7;
    __shared__ float kv[128][4];
    int s = threadIdx.x;            // 128 threads
    const float* qr = qkv + (s*LSEQ + n)*48;
    const float RS2 = 0.70710678118654752f;
    float q0 = qr[hh*2 + 0] * RS2, q1 = qr[hh*2 + 1] * RS2;
    kv[s][0] = qr[16 + hh*2]; kv[s][1] = qr[16 + hh*2 + 1];
    kv[s][2] = qr[32 + hh*2]; kv[s][3] = qr[32 + hh*2 + 1];
    __syncthreads();
    float m = -1e30f, sum = 0.f, o0 = 0.f, o1 = 0.f;
    for (int t = 0; t < 128; t++) {
        float sc = q0*kv[t][0] + q1*kv[t][1];
        float nm = fmaxf(m, sc);
        float cor = expf(m - nm);
        float e = expf(sc - nm);
        sum = sum*cor + e;
        o0 = o0*cor + e*kv[t][2];
        o1 = o1*cor + e*kv[t][3];
        m = nm;
    }
    float inv = 1.f / sum;
    obuf[(s*LSEQ + n)*16 + hh*2 + 0] = o0 * inv;
    obuf[(s*LSEQ + n)*16 + hh*2 + 1] = o1 * inv;
}

// proj + residual + LN1 + FF + residual + LN2 (+ optional transposed final write)
__global__ void k_post(const float* __restrict__ hin, const float* __restrict__ obuf,
                       const float* __restrict__ pw, const float* __restrict__ pb,
                       const float* __restrict__ f1w, const float* __restrict__ f1b,
                       const float* __restrict__ f2w, const float* __restrict__ f2b,
                       const float* __restrict__ lg1, const float* __restrict__ lb1,
                       const float* __restrict__ lg2, const float* __restrict__ lb2,
                       float* __restrict__ hout, float* __restrict__ fout, int writeFinal)
{
    __shared__ float pwl[256], f1wl[1024], f2wl[1024];
    __shared__ float pbl[16], f1bl[64], f2bl[16], g1l[16], b1l[16], g2l[16], b2l[16];
    int tid = threadIdx.x;
    pwl[tid] = pw[tid];
    for (int i = tid; i < 1024; i += 256) { f1wl[i] = f1w[i]; f2wl[i] = f2w[i]; }
    if (tid < 16) {
        pbl[tid] = pb[tid]; f2bl[tid] = f2b[tid];
        g1l[tid] = lg1[tid]; b1l[tid] = lb1[tid];
        g2l[tid] = lg2[tid]; b2l[tid] = lb2[tid];
    }
    if (tid < 64) f1bl[tid] = f1b[tid];
    __syncthreads();
    int r = blockIdx.x * 256 + tid;
    if (r >= BBATCH * LSEQ) return;
    float hv[16], ov[16];
    const float4* hp = (const float4*)(hin + r*16);
    const float4* op = (const float4*)(obuf + r*16);
#pragma unroll
    for (int i = 0; i < 4; i++) {
        float4 a = hp[i];
        hv[4*i] = a.x; hv[4*i+1] = a.y; hv[4*i+2] = a.z; hv[4*i+3] = a.w;
        float4 bq = op[i];
        ov[4*i] = bq.x; ov[4*i+1] = bq.y; ov[4*i+2] = bq.z; ov[4*i+3] = bq.w;
    }
    float h1[16];
#pragma unroll
    for (int c = 0; c < 16; c++) {
        float p = pbl[c];
#pragma unroll
        for (int j = 0; j < 16; j++) p += pwl[c*16 + j] * ov[j];
        h1[c] = hv[c] + p;
    }
    // LN1
    float mn = 0.f;
#pragma unroll
    for (int c = 0; c < 16; c++) mn += h1[c];
    mn *= (1.f/16.f);
    float var = 0.f;
#pragma unroll
    for (int c = 0; c < 16; c++) { float d = h1[c] - mn; var += d*d; }
    var *= (1.f/16.f);
    float rs = rsqrtf(var + 1e-5f);
    float y[16];
#pragma unroll
    for (int c = 0; c < 16; c++) y[c] = (h1[c] - mn)*rs*g1l[c] + b1l[c];
    // FF
    float t2[16];
#pragma unroll
    for (int c = 0; c < 16; c++) t2[c] = f2bl[c];
    for (int u = 0; u < 64; u++) {
        float s = f1bl[u];
#pragma unroll
        for (int c = 0; c < 16; c++) s += f1wl[u*16 + c] * y[c];
        s = fmaxf(s, 0.f);
#pragma unroll
        for (int c = 0; c < 16; c++) t2[c] += f2wl[c*64 + u] * s;
    }
    float h2[16];
#pragma unroll
    for (int c = 0; c < 16; c++) h2[c] = y[c] + t2[c];
    // LN2
    mn = 0.f;
#pragma unroll
    for (int c = 0; c < 16; c++) mn += h2[c];
    mn *= (1.f/16.f);
    var = 0.f;
#pragma unroll
    for (int c = 0; c < 16; c++) { float d = h2[c] - mn; var += d*d; }
    var *= (1.f/16.f);
    rs = rsqrtf(var + 1e-5f);
    float z[16];
#pragma unroll
    for (int c = 0; c < 16; c++) z[c] = (h2[c] - mn)*rs*g2l[c] + b2l[c];
#pragma unroll
    for (int c = 0; c < 16; c++) hout[r*16 + c] = z[c];
    if (writeFinal) {
        int b = r / LSEQ, n = r % LSEQ;
#pragma unroll
        for (int c = 0; c < 16; c++) fout[(b*16 + c)*LSEQ + n] = z[c];
    }
}

extern "C" void kernel_launch(void* const* d_in, const int* in_sizes, int n_in,
                              void* d_out, int out_size, void* d_ws, size_t ws_size,
                              hipStream_t stream)
{
    const float* x       = (const float*)d_in[0];
    const float* w_spec1 = (const float*)d_in[1];
    const float* b_spec1 = (const float*)d_in[2];
    const float* w_spec2 = (const float*)d_in[3];
    const float* b_spec2 = (const float*)d_in[4];
    const float* g_bn1   = (const float*)d_in[5];
    const float* b_bn1   = (const float*)d_in[6];
    const float* g_bn2   = (const float*)d_in[7];
    const float* b_bn2   = (const float*)d_in[8];
    const float* w_sp1a  = (const float*)d_in[9];
    const float* g_bn3   = (const float*)d_in[10];
    const float* b_bn3   = (const float*)d_in[11];
    const float* w_sp1b  = (const float*)d_in[12];
    const float* b_sp1b  = (const float*)d_in[13];
    const float* g_bn4   = (const float*)d_in[14];
    const float* b_bn4   = (const float*)d_in[15];
    const float* w_sp2   = (const float*)d_in[16];
    const float* b_sp2   = (const float*)d_in[17];
    const float* g_bn5   = (const float*)d_in[18];
    const float* b_bn5   = (const float*)d_in[19];
    const float* Amat    = (const float*)d_in[20];
    const float* Bmat    = (const float*)d_in[21];
    const float* Cmat    = (const float*)d_in[22];
    const float* qkv_w   = (const float*)d_in[23];
    const float* qkv_b   = (const float*)d_in[24];
    const float* proj_w  = (const float*)d_in[25];
    const float* proj_b  = (const float*)d_in[26];
    const float* ff1_w   = (const float*)d_in[27];
    const float* ff1_b   = (const float*)d_in[28];
    const float* ff2_w   = (const float*)d_in[29];
    const float* ff2_b   = (const float*)d_in[30];
    const float* ln1_g   = (const float*)d_in[31];
    const float* ln1_b   = (const float*)d_in[32];
    const float* ln2_g   = (const float*)d_in[33];
    const float* ln2_b   = (const float*)d_in[34];

    float* ws  = (float*)d_ws;
    float* out = (float*)d_out;

    float* consts = ws + OFF_CONST;
    float* bufA   = ws + OFF_BUFA;
    float* bufB   = ws + OFF_BUFB;
    float* seq    = ws + OFF_SEQ;
    float* hbuf   = ws + OFF_HBUF;
    float* qkv    = ws + OFF_QKV;
    float* obuf   = ws + OFF_OBUF;

    k_setup<<<1, 256, 0, stream>>>(w_sp1a, b_spec1, g_bn1, b_bn1, g_bn3, b_bn3,
                                   w_spec2, b_spec2, g_bn2, b_bn2,
                                   w_sp2, b_sp2, g_bn5, b_bn5, consts);
    k_mix1<<<BBATCH*16, 256, 0, stream>>>(x, w_sp1a, bufA);
    k_conv125<<<BBATCH*16, 256, 0, stream>>>(bufA, w_spec1, consts, bufB);
    k_pw<<<(BBATCH*TLEN)/256, 256, 0, stream>>>(bufB, w_sp1b, b_sp1b, g_bn4, b_bn4, bufA);
    k_pool1<<<(BBATCH*16*L1W + 255)/256, 256, 0, stream>>>(bufA, seq);
    k_b2conv<<<BBATCH*16, 256, 0, stream>>>(x, consts, bufB);
    k_pool2<<<(BBATCH*16*L2W + 255)/256, 256, 0, stream>>>(bufB, seq);
    k_ssm<<<BBATCH/16, 256, 0, stream>>>(seq, Amat, Bmat, Cmat, hbuf);

    for (int l = 0; l < 2; l++) {
        k_qkv<<<(BBATCH*LSEQ + 255)/256, 256, 0, stream>>>(hbuf, qkv_w + l*768, qkv_b + l*48, qkv);
        k_attn<<<LSEQ*NHEAD, 128, 0, stream>>>(qkv, obuf);
        k_post<<<(BBATCH*LSEQ + 255)/256, 256, 0, stream>>>(hbuf, obuf,
            proj_w + l*256, proj_b + l*16,
            ff1_w + l*1024, ff1_b + l*64,
            ff2_w + l*1024, ff2_b + l*16,
            ln1_g + l*16, ln1_b + l*16,
            ln2_g + l*16, ln2_b + l*16,
            hbuf, out, (l == 1) ? 1 : 0);
    }
}

// Round 2
// 405.968 us; speedup vs baseline: 1.0228x; 1.0228x over previous
//
#include <hip/hip_runtime.h>
#include <hip/hip_bf16.h>
#include <math.h>

// Problem dims
#define BBATCH 128
#define NCHAN  22
#define TLEN   1000
#define F1C    8
#define F2C    16
#define L1W    31
#define L2W    38
#define LSEQ   69
#define EDIM   16
#define NHEAD  8
#define FFDIM  64

// const block offsets (in floats, within ws)
#define C_SA   0
#define C_BA   16
#define C_BC2  32
#define C_W2F  48
#define C_W1P  (48 + 16*22*30)          // 10608: padded 8 x 128 spec1 filters
#define C_TOTAL (C_W1P + 8*128)

// ws layout (floats)
#define OFF_CONST 0
#define OFF_BUFA  16384
#define OFF_BUFB  (OFF_BUFA + 2048000)
#define OFF_SEQ   (OFF_BUFB + 2048000)
#define OFF_HBUF  (OFF_SEQ + 141312)
// qkv and obuf alias bufA (dead after pool1)
#define OFF_QKV   OFF_BUFA
#define OFF_OBUF  (OFF_BUFA + 423936)

// ---------------- setup: fold BN + compose branch-2 filter + pad spec1 -----
__global__ void k_setup(const float* __restrict__ wsp1a, const float* __restrict__ b_spec1,
                        const float* __restrict__ g_bn1, const float* __restrict__ b_bn1,
                        const float* __restrict__ g_bn3, const float* __restrict__ b_bn3,
                        const float* __restrict__ w_spec2, const float* __restrict__ b_spec2,
                        const float* __restrict__ g_bn2, const float* __restrict__ b_bn2,
                        const float* __restrict__ w_sp2, const float* __restrict__ b_sp2,
                        const float* __restrict__ g_bn5, const float* __restrict__ b_bn5,
                        const float* __restrict__ w_spec1,
                        float* __restrict__ consts)
{
    int tid = threadIdx.x;
    float rbn = rsqrtf(1.0f + 1e-5f);
    if (tid < 16) {
        int c2 = tid, c1 = c2 >> 1;
        float wsum = 0.f;
        for (int h = 0; h < NCHAN; h++) wsum += wsp1a[c2*NCHAN + h];
        float s1b = g_bn1[c1] * rbn;
        float s3  = g_bn3[c2] * rbn;
        float C1  = (s1b * b_spec1[c1] + b_bn1[c1]) * wsum;
        consts[C_SA + c2] = s3 * s1b;
        consts[C_BA + c2] = s3 * C1 + b_bn3[c2];
        // branch-2 bias
        float s5 = g_bn5[c2] * rbn;
        float acc = b_sp2[c2];
        for (int cc = 0; cc < F1C; cc++) {
            float s2b = g_bn2[cc] * rbn;
            float cb  = s2b * b_spec2[cc] + b_bn2[cc];
            float wsh = 0.f;
            for (int h = 0; h < NCHAN; h++) wsh += w_sp2[(c2*F1C + cc)*NCHAN + h];
            acc += wsh * cb;
        }
        consts[C_BC2 + c2] = s5 * acc + b_bn5[c2];
    }
    for (int idx = tid; idx < 16*22*30; idx += 256) {
        int c2 = idx / 660;
        int rem = idx % 660;
        int h = rem / 30, k = rem % 30;
        float s5 = g_bn5[c2] * rbn;
        float s = 0.f;
        for (int cc = 0; cc < F1C; cc++)
            s += w_sp2[(c2*F1C + cc)*NCHAN + h] * (g_bn2[cc] * rbn) * w_spec2[cc*30 + k];
        consts[C_W2F + idx] = s5 * s;
    }
    // padded spec1 filters: 8 x 128, taps 125..127 = 0
    for (int idx = tid; idx < 8*128; idx += 256) {
        int c1 = idx >> 7, k = idx & 127;
        consts[C_W1P + idx] = (k < 125) ? w_spec1[c1*125 + k] : 0.f;
    }
}

// ------------- branch 1: fused h-mix + 125-tap conv + affine + ELU --------
// grid: (b*16 + c2) = 2048 blocks, 128 threads. Each lane computes 8 t.
#define ROWSZ 1136
__global__ void k_conv125f(const float* __restrict__ x, const float* __restrict__ wsp1a,
                           const float* __restrict__ consts, float* __restrict__ e1)
{
    __shared__ __align__(16) float row[ROWSZ];
    int bid = blockIdx.x;           // b*16 + c2
    int c2 = bid & 15, b = bid >> 4, c1 = c2 >> 1;
    int tid = threadIdx.x;          // 128 threads

    // zero the unstaged tail [1126, ROWSZ)
    for (int i = 1126 + tid; i < ROWSZ; i += 128) row[i] = 0.f;

    // preload mixing weights (uniform -> SGPRs)
    float wl[NCHAN];
#pragma unroll
    for (int h = 0; h < NCHAN; h++) wl[h] = wsp1a[c2*NCHAN + h];

    // stage mixed row: row[i] = sum_h wl[h]*x[b][h][i-62], zero outside.
    // process in t-aligned float4 groups t4 = -64 + 4g, g in [0,282)
    for (int g = tid; g < 282; g += 128) {
        int t4 = -64 + g*4;
        float m0 = 0.f, m1 = 0.f, m2 = 0.f, m3 = 0.f;
        if (t4 >= 0 && t4 <= 996) {
#pragma unroll
            for (int h = 0; h < NCHAN; h++) {
                const float4 v = *(const float4*)(x + (b*NCHAN + h)*TLEN + t4);
                float w = wl[h];
                m0 += w*v.x; m1 += w*v.y; m2 += w*v.z; m3 += w*v.w;
            }
        } else {
#pragma unroll
            for (int h = 0; h < NCHAN; h++) {
                const float* xr = x + (b*NCHAN + h)*TLEN;
                float w = wl[h];
                if ((unsigned)(t4+0) < 1000u) m0 += w*xr[t4+0];
                if ((unsigned)(t4+1) < 1000u) m1 += w*xr[t4+1];
                if ((unsigned)(t4+2) < 1000u) m2 += w*xr[t4+2];
                if ((unsigned)(t4+3) < 1000u) m3 += w*xr[t4+3];
            }
        }
        int i0 = t4 + 62;
        if (i0 >= 0) {
            row[i0] = m0; row[i0+1] = m1; row[i0+2] = m2; row[i0+3] = m3;
        } else {        // i0 == -2 only
            if (i0+2 >= 0) row[i0+2] = m2;
            if (i0+3 >= 0) row[i0+3] = m3;
        }
    }
    __syncthreads();

    if (tid < 125) {
        int t0 = tid * 8;
        float sa = consts[C_SA + c2], ba = consts[C_BA + c2];
        float acc[8] = {0.f,0.f,0.f,0.f,0.f,0.f,0.f,0.f};
        for (int k0 = 0; k0 < 128; k0 += 4) {
            float4 va = *(const float4*)&row[t0 + k0];
            float4 vb = *(const float4*)&row[t0 + k0 + 4];
            float4 vc = *(const float4*)&row[t0 + k0 + 8];
            float v[12] = {va.x,va.y,va.z,va.w, vb.x,vb.y,vb.z,vb.w, vc.x,vc.y,vc.z,vc.w};
#pragma unroll
            for (int i = 0; i < 4; i++) {
                float w = consts[C_W1P + c1*128 + k0 + i];   // uniform -> s_load
#pragma unroll
                for (int j = 0; j < 8; j++) acc[j] += w * v[i + j];
            }
        }
#pragma unroll
        for (int j = 0; j < 8; j++) {
            float a = sa * acc[j] + ba;
            e1[bid*TLEN + t0 + j] = (a > 0.f) ? a : (expf(a) - 1.f);
        }
    }
}

// pointwise 16x16 conv + bn4 + ELU
__global__ void k_pw(const float* __restrict__ e1, const float* __restrict__ w_sp1b,
                     const float* __restrict__ b_sp1b, const float* __restrict__ g_bn4,
                     const float* __restrict__ b_bn4, float* __restrict__ g1out)
{
    __shared__ float wb[256];
    __shared__ float sb[16], bb[16];
    int tid = threadIdx.x;
    wb[tid] = w_sp1b[tid];
    if (tid < 16) {
        float rbn = rsqrtf(1.0f + 1e-5f);
        float s = g_bn4[tid] * rbn;
        sb[tid] = s;
        bb[tid] = s * b_sp1b[tid] + b_bn4[tid];
    }
    __syncthreads();
    int idx = blockIdx.x * 256 + tid;   // over (b,t): 128*1000
    if (idx >= BBATCH * TLEN) return;
    int t = idx % TLEN, b = idx / TLEN;
    float ev[16];
#pragma unroll
    for (int j = 0; j < 16; j++) ev[j] = e1[(b*16 + j)*TLEN + t];
#pragma unroll
    for (int c = 0; c < 16; c++) {
        float s = 0.f;
#pragma unroll
        for (int j = 0; j < 16; j++) s += wb[c*16 + j] * ev[j];
        float a = sb[c] * s + bb[c];
        g1out[(b*16 + c)*TLEN + t] = (a > 0.f) ? a : (expf(a) - 1.f);
    }
}

// avgpool 32/32 -> seq[:, 0:31, :]
__global__ void k_pool1(const float* __restrict__ g1, float* __restrict__ seq)
{
    int idx = blockIdx.x * 256 + threadIdx.x;   // 128*16*31
    if (idx >= BBATCH * 16 * L1W) return;
    int tw = idx % L1W;
    int c2 = (idx / L1W) & 15;
    int b = idx / (16 * L1W);
    const float* g = g1 + (b*16 + c2)*TLEN + 32*tw;
    float s = 0.f;
#pragma unroll
    for (int i = 0; i < 32; i++) s += g[i];
    seq[(b*LSEQ + tw)*16 + c2] = s * (1.f/32.f);
}

// ---------------- branch 2: fused conv, stage-once, scalar weights --------
// grid: (b*4 + tq) = 512 blocks, 256 threads; lane = one t of 250.
__global__ void k_b2conv(const float* __restrict__ x, const float* __restrict__ consts,
                         float* __restrict__ v2)
{
    __shared__ float sx[NCHAN * 280];
    int bid = blockIdx.x;           // b*4 + tq
    int tq = bid & 3, b = bid >> 2;
    int t0 = tq * 250;
    int tid = threadIdx.x;

    for (int idx = tid; idx < NCHAN*280; idx += 256) {
        int h = idx / 280, i = idx - h*280;
        int t = t0 - 14 + i;
        sx[idx] = ((unsigned)t < 1000u) ? x[(b*NCHAN + h)*TLEN + t] : 0.f;
    }
    __syncthreads();

    if (tid < 250) {
        float acc[16];
#pragma unroll
        for (int c = 0; c < 16; c++) acc[c] = 0.f;
        for (int h = 0; h < NCHAN; h++) {
            float v[30];
#pragma unroll
            for (int k = 0; k < 30; k++) v[k] = sx[h*280 + tid + k];
#pragma unroll
            for (int c2 = 0; c2 < 16; c2++) {
                const float* w = consts + C_W2F + (c2*NCHAN + h)*30;  // uniform -> s_load
                float s = 0.f;
#pragma unroll
                for (int k = 0; k < 30; k++) s += w[k] * v[k];
                acc[c2] += s;
            }
        }
        int t = t0 + tid;
#pragma unroll
        for (int c2 = 0; c2 < 16; c2++) {
            float a = acc[c2] + consts[C_BC2 + c2];
            v2[(b*16 + c2)*TLEN + t] = a * a;
        }
    }
}

// avgpool 75/25 + log(clip) -> seq[:, 31:69, :]
__global__ void k_pool2(const float* __restrict__ v2, float* __restrict__ seq)
{
    int idx = blockIdx.x * 256 + threadIdx.x;   // 128*16*38
    if (idx >= BBATCH * 16 * L2W) return;
    int tw = idx % L2W;
    int c2 = (idx / L2W) & 15;
    int b = idx / (16 * L2W);
    const float* v = v2 + (b*16 + c2)*TLEN + 25*tw;
    float s = 0.f;
    for (int i = 0; i < 75; i++) s += v[i];
    float m = s * (1.f/75.f);
    seq[(b*LSEQ + 31 + tw)*16 + c2] = logf(fmaxf(m, 1e-6f));
}

// ---------------- linear SSM scan ----------------
__global__ void k_ssm(const float* __restrict__ seq, const float* __restrict__ Amat,
                      const float* __restrict__ Bmat, const float* __restrict__ Cmat,
                      float* __restrict__ hbuf)
{
    __shared__ float Al[256], Bl[256], Cl[256];
    __shared__ float st[16][17], xt[16][17];
    int tid = threadIdx.x;
    Al[tid] = Amat[tid]; Bl[tid] = Bmat[tid]; Cl[tid] = Cmat[tid];
    int bb = tid >> 4, j = tid & 15;
    int b = blockIdx.x * 16 + bb;
    st[bb][j] = 0.f;
    __syncthreads();
    for (int l = 0; l < LSEQ; l++) {
        xt[bb][j] = seq[(b*LSEQ + l)*16 + j];
        __syncthreads();
        float nv = 0.f;
#pragma unroll
        for (int i = 0; i < 16; i++)
            nv += st[bb][i]*Al[i*16 + j] + xt[bb][i]*Bl[j*16 + i];
        __syncthreads();
        st[bb][j] = nv;
        __syncthreads();
        float ov = 0.f;
#pragma unroll
        for (int i = 0; i < 16; i++) ov += st[bb][i]*Cl[j*16 + i];
        hbuf[(b*LSEQ + l)*16 + j] = ov;
    }
}

// ---------------- transformer: qkv projection ----------------
__global__ void k_qkv(const float* __restrict__ h, const float* __restrict__ qkvw,
                      const float* __restrict__ qkvb, float* __restrict__ qkv)
{
    __shared__ float wl[768];
    __shared__ float bl[48];
    int tid = threadIdx.x;
    for (int i = tid; i < 768; i += 256) wl[i] = qkvw[i];
    if (tid < 48) bl[tid] = qkvb[tid];
    __syncthreads();
    int r = blockIdx.x * 256 + tid;
    if (r >= BBATCH * LSEQ) return;
    float hv[16];
    const float4* hp = (const float4*)(h + r*16);
#pragma unroll
    for (int i = 0; i < 4; i++) {
        float4 a = hp[i];
        hv[4*i] = a.x; hv[4*i+1] = a.y; hv[4*i+2] = a.z; hv[4*i+3] = a.w;
    }
#pragma unroll
    for (int o = 0; o < 48; o++) {
        float s = bl[o];
#pragma unroll
        for (int c = 0; c < 16; c++) s += wl[o*16 + c] * hv[c];
        qkv[r*48 + o] = s;
    }
}

// attention over the batch axis: per (n, head), S=T=128, hd=2
__global__ void k_attn(const float* __restrict__ qkv, float* __restrict__ obuf)
{
    int n = blockIdx.x >> 3, hh = blockIdx.x & 7;
    __shared__ float kv[128][4];
    int s = threadIdx.x;            // 128 threads
    const float* qr = qkv + (s*LSEQ + n)*48;
    const float RS2 = 0.70710678118654752f;
    float q0 = qr[hh*2 + 0] * RS2, q1 = qr[hh*2 + 1] * RS2;
    kv[s][0] = qr[16 + hh*2]; kv[s][1] = qr[16 + hh*2 + 1];
    kv[s][2] = qr[32 + hh*2]; kv[s][3] = qr[32 + hh*2 + 1];
    __syncthreads();
    float m = -1e30f, sum = 0.f, o0 = 0.f, o1 = 0.f;
    for (int t = 0; t < 128; t++) {
        float sc = q0*kv[t][0] + q1*kv[t][1];
        float nm = fmaxf(m, sc);
        float cor = expf(m - nm);
        float e = expf(sc - nm);
        sum = sum*cor + e;
        o0 = o0*cor + e*kv[t][2];
        o1 = o1*cor + e*kv[t][3];
        m = nm;
    }
    float inv = 1.f / sum;
    obuf[(s*LSEQ + n)*16 + hh*2 + 0] = o0 * inv;
    obuf[(s*LSEQ + n)*16 + hh*2 + 1] = o1 * inv;
}

// proj + residual + LN1 + FF + residual + LN2 (+ optional transposed final write)
__global__ void k_post(const float* __restrict__ hin, const float* __restrict__ obuf,
                       const float* __restrict__ pw, const float* __restrict__ pb,
                       const float* __restrict__ f1w, const float* __restrict__ f1b,
                       const float* __restrict__ f2w, const float* __restrict__ f2b,
                       const float* __restrict__ lg1, const float* __restrict__ lb1,
                       const float* __restrict__ lg2, const float* __restrict__ lb2,
                       float* __restrict__ hout, float* __restrict__ fout, int writeFinal)
{
    __shared__ float pwl[256], f1wl[1024], f2wl[1024];
    __shared__ float pbl[16], f1bl[64], f2bl[16], g1l[16], b1l[16], g2l[16], b2l[16];
    int tid = threadIdx.x;
    pwl[tid] = pw[tid];
    for (int i = tid; i < 1024; i += 256) { f1wl[i] = f1w[i]; f2wl[i] = f2w[i]; }
    if (tid < 16) {
        pbl[tid] = pb[tid]; f2bl[tid] = f2b[tid];
        g1l[tid] = lg1[tid]; b1l[tid] = lb1[tid];
        g2l[tid] = lg2[tid]; b2l[tid] = lb2[tid];
    }
    if (tid < 64) f1bl[tid] = f1b[tid];
    __syncthreads();
    int r = blockIdx.x * 256 + tid;
    if (r >= BBATCH * LSEQ) return;
    float hv[16], ov[16];
    const float4* hp = (const float4*)(hin + r*16);
    const float4* op = (const float4*)(obuf + r*16);
#pragma unroll
    for (int i = 0; i < 4; i++) {
        float4 a = hp[i];
        hv[4*i] = a.x; hv[4*i+1] = a.y; hv[4*i+2] = a.z; hv[4*i+3] = a.w;
        float4 bq = op[i];
        ov[4*i] = bq.x; ov[4*i+1] = bq.y; ov[4*i+2] = bq.z; ov[4*i+3] = bq.w;
    }
    float h1[16];
#pragma unroll
    for (int c = 0; c < 16; c++) {
        float p = pbl[c];
#pragma unroll
        for (int j = 0; j < 16; j++) p += pwl[c*16 + j] * ov[j];
        h1[c] = hv[c] + p;
    }
    // LN1
    float mn = 0.f;
#pragma unroll
    for (int c = 0; c < 16; c++) mn += h1[c];
    mn *= (1.f/16.f);
    float var = 0.f;
#pragma unroll
    for (int c = 0; c < 16; c++) { float d = h1[c] - mn; var += d*d; }
    var *= (1.f/16.f);
    float rs = rsqrtf(var + 1e-5f);
    float y[16];
#pragma unroll
    for (int c = 0; c < 16; c++) y[c] = (h1[c] - mn)*rs*g1l[c] + b1l[c];
    // FF
    float t2[16];
#pragma unroll
    for (int c = 0; c < 16; c++) t2[c] = f2bl[c];
    for (int u = 0; u < 64; u++) {
        float s = f1bl[u];
#pragma unroll
        for (int c = 0; c < 16; c++) s += f1wl[u*16 + c] * y[c];
        s = fmaxf(s, 0.f);
#pragma unroll
        for (int c = 0; c < 16; c++) t2[c] += f2wl[c*64 + u] * s;
    }
    float h2[16];
#pragma unroll
    for (int c = 0; c < 16; c++) h2[c] = y[c] + t2[c];
    // LN2
    mn = 0.f;
#pragma unroll
    for (int c = 0; c < 16; c++) mn += h2[c];
    mn *= (1.f/16.f);
    var = 0.f;
#pragma unroll
    for (int c = 0; c < 16; c++) { float d = h2[c] - mn; var += d*d; }
    var *= (1.f/16.f);
    rs = rsqrtf(var + 1e-5f);
    float z[16];
#pragma unroll
    for (int c = 0; c < 16; c++) z[c] = (h2[c] - mn)*rs*g2l[c] + b2l[c];
#pragma unroll
    for (int c = 0; c < 16; c++) hout[r*16 + c] = z[c];
    if (writeFinal) {
        int b = r / LSEQ, n = r % LSEQ;
#pragma unroll
        for (int c = 0; c < 16; c++) fout[(b*16 + c)*LSEQ + n] = z[c];
    }
}

extern "C" void kernel_launch(void* const* d_in, const int* in_sizes, int n_in,
                              void* d_out, int out_size, void* d_ws, size_t ws_size,
                              hipStream_t stream)
{
    const float* x       = (const float*)d_in[0];
    const float* w_spec1 = (const float*)d_in[1];
    const float* b_spec1 = (const float*)d_in[2];
    const float* w_spec2 = (const float*)d_in[3];
    const float* b_spec2 = (const float*)d_in[4];
    const float* g_bn1   = (const float*)d_in[5];
    const float* b_bn1   = (const float*)d_in[6];
    const float* g_bn2   = (const float*)d_in[7];
    const float* b_bn2   = (const float*)d_in[8];
    const float* w_sp1a  = (const float*)d_in[9];
    const float* g_bn3   = (const float*)d_in[10];
    const float* b_bn3   = (const float*)d_in[11];
    const float* w_sp1b  = (const float*)d_in[12];
    const float* b_sp1b  = (const float*)d_in[13];
    const float* g_bn4   = (const float*)d_in[14];
    const float* b_bn4   = (const float*)d_in[15];
    const float* w_sp2   = (const float*)d_in[16];
    const float* b_sp2   = (const float*)d_in[17];
    const float* g_bn5   = (const float*)d_in[18];
    const float* b_bn5   = (const float*)d_in[19];
    const float* Amat    = (const float*)d_in[20];
    const float* Bmat    = (const float*)d_in[21];
    const float* Cmat    = (const float*)d_in[22];
    const float* qkv_w   = (const float*)d_in[23];
    const float* qkv_b   = (const float*)d_in[24];
    const float* proj_w  = (const float*)d_in[25];
    const float* proj_b  = (const float*)d_in[26];
    const float* ff1_w   = (const float*)d_in[27];
    const float* ff1_b   = (const float*)d_in[28];
    const float* ff2_w   = (const float*)d_in[29];
    const float* ff2_b   = (const float*)d_in[30];
    const float* ln1_g   = (const float*)d_in[31];
    const float* ln1_b   = (const float*)d_in[32];
    const float* ln2_g   = (const float*)d_in[33];
    const float* ln2_b   = (const float*)d_in[34];

    float* ws  = (float*)d_ws;
    float* out = (float*)d_out;

    float* consts = ws + OFF_CONST;
    float* bufA   = ws + OFF_BUFA;
    float* bufB   = ws + OFF_BUFB;
    float* seq    = ws + OFF_SEQ;
    float* hbuf   = ws + OFF_HBUF;
    float* qkv    = ws + OFF_QKV;
    float* obuf   = ws + OFF_OBUF;

    k_setup<<<1, 256, 0, stream>>>(w_sp1a, b_spec1, g_bn1, b_bn1, g_bn3, b_bn3,
                                   w_spec2, b_spec2, g_bn2, b_bn2,
                                   w_sp2, b_sp2, g_bn5, b_bn5, w_spec1, consts);
    k_conv125f<<<BBATCH*16, 128, 0, stream>>>(x, w_sp1a, consts, bufB);
    k_pw<<<(BBATCH*TLEN + 255)/256, 256, 0, stream>>>(bufB, w_sp1b, b_sp1b, g_bn4, b_bn4, bufA);
    k_pool1<<<(BBATCH*16*L1W + 255)/256, 256, 0, stream>>>(bufA, seq);
    k_b2conv<<<BBATCH*4, 256, 0, stream>>>(x, consts, bufB);
    k_pool2<<<(BBATCH*16*L2W + 255)/256, 256, 0, stream>>>(bufB, seq);
    k_ssm<<<BBATCH/16, 256, 0, stream>>>(seq, Amat, Bmat, Cmat, hbuf);

    for (int l = 0; l < 2; l++) {
        k_qkv<<<(BBATCH*LSEQ + 255)/256, 256, 0, stream>>>(hbuf, qkv_w + l*768, qkv_b + l*48, qkv);
        k_attn<<<LSEQ*NHEAD, 128, 0, stream>>>(qkv, obuf);
        k_post<<<(BBATCH*LSEQ + 255)/256, 256, 0, stream>>>(hbuf, obuf,
            proj_w + l*256, proj_b + l*16,
            ff1_w + l*1024, ff1_b + l*64,
            ff2_w + l*1024, ff2_b + l*16,
            ln1_g + l*16, ln1_b + l*16,
            ln2_g + l*16, ln2_b + l*16,
            hbuf, out, (l == 1) ? 1 : 0);
    }
}

// Round 3
// 256.324 us; speedup vs baseline: 1.6199x; 1.5838x over previous
//
#include <hip/hip_runtime.h>
#include <hip/hip_bf16.h>
#include <math.h>

// Problem dims
#define BBATCH 128
#define NCHAN  22
#define TLEN   1000
#define F1C    8
#define F2C    16
#define L1W    31
#define L2W    38
#define LSEQ   69
#define EDIM   16
#define NHEAD  8
#define FFDIM  64

// const block offsets (floats within ws)
#define C_SA   0
#define C_BA   16
#define C_BC2  32
#define C_W2T  48                       // [(h*30+k)*16 + c2], s5-folded
#define C_W1P  (48 + 16*22*30)          // 10608: padded 8 x 128 spec1 filters
#define C_TOTAL (C_W1P + 8*128)

// ws layout (floats)
#define OFF_CONST 0
#define OFF_CHNK  16384
#define OFF_SEQ   (OFF_CHNK + 81920)
#define OFF_HBUF  (OFF_SEQ + 141312)
#define OFF_OBUF  (OFF_HBUF + 141312)

// ---------------- setup: fold BN + compose weights ----------------
__global__ void k_setup(const float* __restrict__ wsp1a, const float* __restrict__ b_spec1,
                        const float* __restrict__ g_bn1, const float* __restrict__ b_bn1,
                        const float* __restrict__ g_bn3, const float* __restrict__ b_bn3,
                        const float* __restrict__ w_spec2, const float* __restrict__ b_spec2,
                        const float* __restrict__ g_bn2, const float* __restrict__ b_bn2,
                        const float* __restrict__ w_sp2, const float* __restrict__ b_sp2,
                        const float* __restrict__ g_bn5, const float* __restrict__ b_bn5,
                        const float* __restrict__ w_spec1,
                        float* __restrict__ consts)
{
    int tid = threadIdx.x;
    float rbn = rsqrtf(1.0f + 1e-5f);
    if (tid < 16) {
        int c2 = tid, c1 = c2 >> 1;
        float wsum = 0.f;
        for (int h = 0; h < NCHAN; h++) wsum += wsp1a[c2*NCHAN + h];
        float s1b = g_bn1[c1] * rbn;
        float s3  = g_bn3[c2] * rbn;
        float C1  = (s1b * b_spec1[c1] + b_bn1[c1]) * wsum;
        consts[C_SA + c2] = s3 * s1b;
        consts[C_BA + c2] = s3 * C1 + b_bn3[c2];
        float s5 = g_bn5[c2] * rbn;
        float acc = b_sp2[c2];
        for (int cc = 0; cc < F1C; cc++) {
            float s2b = g_bn2[cc] * rbn;
            float cb  = s2b * b_spec2[cc] + b_bn2[cc];
            float wsh = 0.f;
            for (int h = 0; h < NCHAN; h++) wsh += w_sp2[(c2*F1C + cc)*NCHAN + h];
            acc += wsh * cb;
        }
        consts[C_BC2 + c2] = s5 * acc + b_bn5[c2];
    }
    // transposed branch-2 filter: W2T[(h*30+k)*16 + c2]
    for (int idx = tid; idx < 16*22*30; idx += 256) {
        int c2 = idx & 15;
        int hk = idx >> 4;
        int h = hk / 30, k = hk % 30;
        float s5 = g_bn5[c2] * rbn;
        float s = 0.f;
        for (int cc = 0; cc < F1C; cc++)
            s += w_sp2[(c2*F1C + cc)*NCHAN + h] * (g_bn2[cc] * rbn) * w_spec2[cc*30 + k];
        consts[C_W2T + idx] = s5 * s;
    }
    // padded spec1 filters: 8 x 128, taps 125..127 = 0
    for (int idx = tid; idx < 8*128; idx += 256) {
        int c1 = idx >> 7, k = idx & 127;
        consts[C_W1P + idx] = (k < 125) ? w_spec1[c1*125 + k] : 0.f;
    }
}

// ---------------- branch 1 fully fused ----------------
// grid: (b*4 + q), 256 threads. q covers t [256q, 256q+NT), NT=256 (q<3) / 224.
#define P1 388
#define P2 260
#define PW 132
__global__ void k_b1f(const float* __restrict__ x, const float* __restrict__ wsp1a,
                      const float* __restrict__ consts,
                      const float* __restrict__ w_sp1b, const float* __restrict__ b_sp1b,
                      const float* __restrict__ g_bn4, const float* __restrict__ b_bn4,
                      float* __restrict__ seq)
{
    __shared__ __align__(16) float mrow[16*P1];
    __shared__ __align__(16) float econv[16*P2];
    __shared__ float wlds[8*PW];
    int bid = blockIdx.x;
    int q = bid & 3, b = bid >> 2;
    int tid = threadIdx.x;
    int t0 = q * 256;
    int NT = (q == 3) ? 224 : 256;
    int NCOL = NT + 124;

    // ---- phase A: mixed rows ----
    for (int j = tid; j < NCOL; j += 256) {
        int t = t0 - 62 + j;
        float xv[NCHAN];
#pragma unroll
        for (int h = 0; h < NCHAN; h++)
            xv[h] = ((unsigned)t < 1000u) ? x[(b*NCHAN + h)*TLEN + t] : 0.f;
#pragma unroll
        for (int c2 = 0; c2 < 16; c2++) {
            float s = 0.f;
#pragma unroll
            for (int h = 0; h < NCHAN; h++) s += wsp1a[c2*NCHAN + h] * xv[h];
            mrow[c2*P1 + j] = s;
        }
    }
    // zero pad cols [NCOL, P1)
    for (int j = NCOL + tid; j < P1; j += 256) {
#pragma unroll
        for (int c2 = 0; c2 < 16; c2++) mrow[c2*P1 + j] = 0.f;
    }
    // copy padded filters to LDS (pitch 132 to spread banks)
    for (int i = tid; i < 1024; i += 256)
        wlds[(i >> 7)*PW + (i & 127)] = consts[C_W1P + i];
    __syncthreads();

    // ---- phase B: 125-tap conv + affine + ELU ----
    {
        int c2 = tid & 15, seg = tid >> 4, c1 = c2 >> 1;
        if (seg < (NT >> 4)) {
            int u0 = seg * 16;
            const float* mr = &mrow[c2*P1 + u0];
            float sa = consts[C_SA + c2], ba = consts[C_BA + c2];
            float v[20];
            {
                float4 a0 = *(const float4*)&mr[0];
                float4 a1 = *(const float4*)&mr[4];
                float4 a2 = *(const float4*)&mr[8];
                float4 a3 = *(const float4*)&mr[12];
                float4 a4 = *(const float4*)&mr[16];
                v[0]=a0.x; v[1]=a0.y; v[2]=a0.z; v[3]=a0.w;
                v[4]=a1.x; v[5]=a1.y; v[6]=a1.z; v[7]=a1.w;
                v[8]=a2.x; v[9]=a2.y; v[10]=a2.z; v[11]=a2.w;
                v[12]=a3.x; v[13]=a3.y; v[14]=a3.z; v[15]=a3.w;
                v[16]=a4.x; v[17]=a4.y; v[18]=a4.z; v[19]=a4.w;
            }
            float acc[16];
#pragma unroll
            for (int u = 0; u < 16; u++) acc[u] = 0.f;
#pragma unroll
            for (int k0 = 0; k0 < 128; k0 += 4) {
                float w0 = wlds[c1*PW + k0 + 0];
                float w1 = wlds[c1*PW + k0 + 1];
                float w2 = wlds[c1*PW + k0 + 2];
                float w3 = wlds[c1*PW + k0 + 3];
#pragma unroll
                for (int u = 0; u < 16; u++) {
                    acc[u] += w0 * v[u+0];
                    acc[u] += w1 * v[u+1];
                    acc[u] += w2 * v[u+2];
                    acc[u] += w3 * v[u+3];
                }
                if (k0 < 124) {
#pragma unroll
                    for (int i = 0; i < 16; i++) v[i] = v[i+4];
                    float4 nv = *(const float4*)&mr[k0 + 20];
                    v[16]=nv.x; v[17]=nv.y; v[18]=nv.z; v[19]=nv.w;
                }
            }
            float e[16];
#pragma unroll
            for (int u = 0; u < 16; u++) {
                float a = sa * acc[u] + ba;
                e[u] = (a > 0.f) ? a : (expf(a) - 1.f);
            }
            float* ec = &econv[c2*P2 + u0];
#pragma unroll
            for (int i = 0; i < 4; i++)
                *(float4*)&ec[4*i] = make_float4(e[4*i], e[4*i+1], e[4*i+2], e[4*i+3]);
        }
    }
    __syncthreads();

    // ---- phase C: pointwise 16x16 + bn4 + ELU + pool32 ----
    if (tid < NT) {
        int u = tid;
        float rbn = rsqrtf(1.0f + 1e-5f);
        float hv[16];
#pragma unroll
        for (int c = 0; c < 16; c++) hv[c] = econv[c*P2 + u];
        float p[16];
#pragma unroll
        for (int c = 0; c < 16; c++) {
            float s = 0.f;
#pragma unroll
            for (int j = 0; j < 16; j++) s += w_sp1b[c*16 + j] * hv[j];
            float sc = g_bn4[c] * rbn;
            float a = sc * (s + b_sp1b[c]) + b_bn4[c];
            float g = (a > 0.f) ? a : (expf(a) - 1.f);
            // pool over 32-lane group
            g += __shfl_xor(g, 1, 64);
            g += __shfl_xor(g, 2, 64);
            g += __shfl_xor(g, 4, 64);
            g += __shfl_xor(g, 8, 64);
            g += __shfl_xor(g, 16, 64);
            p[c] = g;
        }
        if ((u & 31) == 0) {
            int w = 8*q + (u >> 5);
            float* sp = &seq[(b*LSEQ + w)*16];
#pragma unroll
            for (int i = 0; i < 4; i++)
                *(float4*)&sp[4*i] = make_float4(p[4*i]*(1.f/32.f), p[4*i+1]*(1.f/32.f),
                                                 p[4*i+2]*(1.f/32.f), p[4*i+3]*(1.f/32.f));
        }
    }
}

// ---------------- branch 2: fused conv + square + 25-chunk sums ----------
// grid: (b*4 + tq) = 512 blocks, 256 threads; lane = one t of 250.
__global__ void k_b2conv(const float* __restrict__ x, const float* __restrict__ consts,
                         float* __restrict__ chnk)
{
    __shared__ float sx[NCHAN * 280];
    __shared__ float sq[16 * 252];
    int bid = blockIdx.x;
    int tq = bid & 3, b = bid >> 2;
    int t0 = tq * 250;
    int tid = threadIdx.x;

    for (int idx = tid; idx < NCHAN*280; idx += 256) {
        int h = idx / 280, i = idx - h*280;
        int t = t0 - 14 + i;
        sx[idx] = ((unsigned)t < 1000u) ? x[(b*NCHAN + h)*TLEN + t] : 0.f;
    }
    __syncthreads();

    if (tid < 250) {
        float acc[16];
#pragma unroll
        for (int c = 0; c < 16; c++) acc[c] = 0.f;
        for (int h = 0; h < NCHAN; h++) {
            const float* sp = &sx[h*280 + tid];
            const float* wp = consts + C_W2T + h*480;   // (h*30+k)*16
#pragma unroll
            for (int k = 0; k < 30; k++) {
                float vk = sp[k];
#pragma unroll
                for (int c2 = 0; c2 < 16; c2++)
                    acc[c2] += wp[k*16 + c2] * vk;      // uniform scalar weight
            }
        }
#pragma unroll
        for (int c2 = 0; c2 < 16; c2++) {
            float a = acc[c2] + consts[C_BC2 + c2];
            sq[c2*252 + tid] = a * a;
        }
    }
    __syncthreads();

    // 25-wide chunk sums: 16 c2 x 10 chunks
    if (tid < 160) {
        int c2 = tid / 10, ch = tid % 10;
        const float* s = &sq[c2*252 + ch*25];
        float acc = 0.f;
#pragma unroll
        for (int i = 0; i < 25; i++) acc += s[i];
        chnk[(b*16 + c2)*40 + tq*10 + ch] = acc;
    }
}

// pool2 from chunk sums: window w = chunks w, w+1, w+2
__global__ void k_pool2(const float* __restrict__ chnk, float* __restrict__ seq)
{
    int idx = blockIdx.x * 256 + threadIdx.x;   // 128*16*38
    if (idx >= BBATCH * 16 * L2W) return;
    int w = idx % L2W;
    int c2 = (idx / L2W) & 15;
    int b = idx / (16 * L2W);
    const float* cp = chnk + (b*16 + c2)*40;
    float m = (cp[w] + cp[w+1] + cp[w+2]) * (1.f/75.f);
    seq[(b*LSEQ + 31 + w)*16 + c2] = logf(fmaxf(m, 1e-6f));
}

// ---------------- linear SSM scan: 16-lane groups, shuffle-based ----------
// grid: 16 blocks x 128 threads; each 16-lane group = one b.
__global__ void k_ssm(const float* __restrict__ seq, const float* __restrict__ Amat,
                      const float* __restrict__ Bmat, const float* __restrict__ Cmat,
                      float* __restrict__ hbuf)
{
    int tid = threadIdx.x;
    int j = tid & 15;
    int b = blockIdx.x * 8 + (tid >> 4);
    int gb = tid & 48;                  // group base within wave
    float Acol[16], Brow[16], Crow[16];
#pragma unroll
    for (int i = 0; i < 16; i++) {
        Acol[i] = Amat[i*16 + j];
        Brow[i] = Bmat[j*16 + i];
        Crow[i] = Cmat[j*16 + i];
    }
    float st = 0.f;
    for (int l = 0; l < LSEQ; l++) {
        float xv = seq[(b*LSEQ + l)*16 + j];
        float nv = 0.f;
#pragma unroll
        for (int i = 0; i < 16; i++) {
            nv += __shfl(st, gb + i, 64) * Acol[i];
            nv += __shfl(xv, gb + i, 64) * Brow[i];
        }
        st = nv;
        float y = 0.f;
#pragma unroll
        for (int i = 0; i < 16; i++)
            y += __shfl(st, gb + i, 64) * Crow[i];
        hbuf[(b*LSEQ + l)*16 + j] = y;
    }
}

// ---------------- attention (qkv fused in) over batch axis ----------------
__global__ void k_attnf(const float* __restrict__ h, const float* __restrict__ qw,
                        const float* __restrict__ qb, float* __restrict__ obuf)
{
    int n = blockIdx.x >> 3, hh = blockIdx.x & 7;
    __shared__ float kv[128][4];
    int s = threadIdx.x;            // 128 threads
    const float* hr = h + (s*LSEQ + n)*16;
    float hv[16];
#pragma unroll
    for (int i = 0; i < 4; i++) {
        float4 a = *(const float4*)&hr[4*i];
        hv[4*i]=a.x; hv[4*i+1]=a.y; hv[4*i+2]=a.z; hv[4*i+3]=a.w;
    }
    int r0 = 2*hh;
    float pr[6];
#pragma unroll
    for (int d = 0; d < 6; d++) {
        int row = (d >> 1)*16 + r0 + (d & 1);
        float sum = qb[row];
#pragma unroll
        for (int c = 0; c < 16; c++) sum += qw[row*16 + c] * hv[c];
        pr[d] = sum;
    }
    const float RS2 = 0.70710678118654752f;
    float q0 = pr[0]*RS2, q1 = pr[1]*RS2;
    *(float4*)&kv[s][0] = make_float4(pr[2], pr[3], pr[4], pr[5]);
    __syncthreads();
    float m = -1e30f, sum = 0.f, o0 = 0.f, o1 = 0.f;
    for (int t = 0; t < 128; t++) {
        float sc = q0*kv[t][0] + q1*kv[t][1];
        float nm = fmaxf(m, sc);
        float cor = expf(m - nm);
        float e = expf(sc - nm);
        sum = sum*cor + e;
        o0 = o0*cor + e*kv[t][2];
        o1 = o1*cor + e*kv[t][3];
        m = nm;
    }
    float inv = 1.f / sum;
    obuf[(s*LSEQ + n)*16 + r0 + 0] = o0 * inv;
    obuf[(s*LSEQ + n)*16 + r0 + 1] = o1 * inv;
}

// proj + residual + LN1 + FF + residual + LN2 (+ optional transposed final write)
__global__ void k_post(const float* __restrict__ hin, const float* __restrict__ obuf,
                       const float* __restrict__ pw, const float* __restrict__ pb,
                       const float* __restrict__ f1w, const float* __restrict__ f1b,
                       const float* __restrict__ f2w, const float* __restrict__ f2b,
                       const float* __restrict__ lg1, const float* __restrict__ lb1,
                       const float* __restrict__ lg2, const float* __restrict__ lb2,
                       float* __restrict__ hout, float* __restrict__ fout, int writeFinal)
{
    __shared__ float pwl[256], f1wl[1024], f2wl[1024];
    __shared__ float pbl[16], f1bl[64], f2bl[16], g1l[16], b1l[16], g2l[16], b2l[16];
    int tid = threadIdx.x;
    pwl[tid] = pw[tid];
    for (int i = tid; i < 1024; i += 256) { f1wl[i] = f1w[i]; f2wl[i] = f2w[i]; }
    if (tid < 16) {
        pbl[tid] = pb[tid]; f2bl[tid] = f2b[tid];
        g1l[tid] = lg1[tid]; b1l[tid] = lb1[tid];
        g2l[tid] = lg2[tid]; b2l[tid] = lb2[tid];
    }
    if (tid < 64) f1bl[tid] = f1b[tid];
    __syncthreads();
    int r = blockIdx.x * 256 + tid;
    if (r >= BBATCH * LSEQ) return;
    float hv[16], ov[16];
    const float4* hp = (const float4*)(hin + r*16);
    const float4* op = (const float4*)(obuf + r*16);
#pragma unroll
    for (int i = 0; i < 4; i++) {
        float4 a = hp[i];
        hv[4*i] = a.x; hv[4*i+1] = a.y; hv[4*i+2] = a.z; hv[4*i+3] = a.w;
        float4 bq = op[i];
        ov[4*i] = bq.x; ov[4*i+1] = bq.y; ov[4*i+2] = bq.z; ov[4*i+3] = bq.w;
    }
    float h1[16];
#pragma unroll
    for (int c = 0; c < 16; c++) {
        float p = pbl[c];
#pragma unroll
        for (int j = 0; j < 16; j++) p += pwl[c*16 + j] * ov[j];
        h1[c] = hv[c] + p;
    }
    float mn = 0.f;
#pragma unroll
    for (int c = 0; c < 16; c++) mn += h1[c];
    mn *= (1.f/16.f);
    float var = 0.f;
#pragma unroll
    for (int c = 0; c < 16; c++) { float d = h1[c] - mn; var += d*d; }
    var *= (1.f/16.f);
    float rs = rsqrtf(var + 1e-5f);
    float y[16];
#pragma unroll
    for (int c = 0; c < 16; c++) y[c] = (h1[c] - mn)*rs*g1l[c] + b1l[c];
    float t2[16];
#pragma unroll
    for (int c = 0; c < 16; c++) t2[c] = f2bl[c];
    for (int u = 0; u < 64; u++) {
        float s = f1bl[u];
#pragma unroll
        for (int c = 0; c < 16; c++) s += f1wl[u*16 + c] * y[c];
        s = fmaxf(s, 0.f);
#pragma unroll
        for (int c = 0; c < 16; c++) t2[c] += f2wl[c*64 + u] * s;
    }
    float h2[16];
#pragma unroll
    for (int c = 0; c < 16; c++) h2[c] = y[c] + t2[c];
    mn = 0.f;
#pragma unroll
    for (int c = 0; c < 16; c++) mn += h2[c];
    mn *= (1.f/16.f);
    var = 0.f;
#pragma unroll
    for (int c = 0; c < 16; c++) { float d = h2[c] - mn; var += d*d; }
    var *= (1.f/16.f);
    rs = rsqrtf(var + 1e-5f);
    float z[16];
#pragma unroll
    for (int c = 0; c < 16; c++) z[c] = (h2[c] - mn)*rs*g2l[c] + b2l[c];
#pragma unroll
    for (int c = 0; c < 16; c++) hout[r*16 + c] = z[c];
    if (writeFinal) {
        int b = r / LSEQ, n = r % LSEQ;
#pragma unroll
        for (int c = 0; c < 16; c++) fout[(b*16 + c)*LSEQ + n] = z[c];
    }
}

extern "C" void kernel_launch(void* const* d_in, const int* in_sizes, int n_in,
                              void* d_out, int out_size, void* d_ws, size_t ws_size,
                              hipStream_t stream)
{
    const float* x       = (const float*)d_in[0];
    const float* w_spec1 = (const float*)d_in[1];
    const float* b_spec1 = (const float*)d_in[2];
    const float* w_spec2 = (const float*)d_in[3];
    const float* b_spec2 = (const float*)d_in[4];
    const float* g_bn1   = (const float*)d_in[5];
    const float* b_bn1   = (const float*)d_in[6];
    const float* g_bn2   = (const float*)d_in[7];
    const float* b_bn2   = (const float*)d_in[8];
    const float* w_sp1a  = (const float*)d_in[9];
    const float* g_bn3   = (const float*)d_in[10];
    const float* b_bn3   = (const float*)d_in[11];
    const float* w_sp1b  = (const float*)d_in[12];
    const float* b_sp1b  = (const float*)d_in[13];
    const float* g_bn4   = (const float*)d_in[14];
    const float* b_bn4   = (const float*)d_in[15];
    const float* w_sp2   = (const float*)d_in[16];
    const float* b_sp2   = (const float*)d_in[17];
    const float* g_bn5   = (const float*)d_in[18];
    const float* b_bn5   = (const float*)d_in[19];
    const float* Amat    = (const float*)d_in[20];
    const float* Bmat    = (const float*)d_in[21];
    const float* Cmat    = (const float*)d_in[22];
    const float* qkv_w   = (const float*)d_in[23];
    const float* qkv_b   = (const float*)d_in[24];
    const float* proj_w  = (const float*)d_in[25];
    const float* proj_b  = (const float*)d_in[26];
    const float* ff1_w   = (const float*)d_in[27];
    const float* ff1_b   = (const float*)d_in[28];
    const float* ff2_w   = (const float*)d_in[29];
    const float* ff2_b   = (const float*)d_in[30];
    const float* ln1_g   = (const float*)d_in[31];
    const float* ln1_b   = (const float*)d_in[32];
    const float* ln2_g   = (const float*)d_in[33];
    const float* ln2_b   = (const float*)d_in[34];

    float* ws  = (float*)d_ws;
    float* out = (float*)d_out;

    float* consts = ws + OFF_CONST;
    float* chnk   = ws + OFF_CHNK;
    float* seq    = ws + OFF_SEQ;
    float* hbuf   = ws + OFF_HBUF;
    float* obuf   = ws + OFF_OBUF;

    k_setup<<<1, 256, 0, stream>>>(w_sp1a, b_spec1, g_bn1, b_bn1, g_bn3, b_bn3,
                                   w_spec2, b_spec2, g_bn2, b_bn2,
                                   w_sp2, b_sp2, g_bn5, b_bn5, w_spec1, consts);
    k_b1f<<<BBATCH*4, 256, 0, stream>>>(x, w_sp1a, consts, w_sp1b, b_sp1b, g_bn4, b_bn4, seq);
    k_b2conv<<<BBATCH*4, 256, 0, stream>>>(x, consts, chnk);
    k_pool2<<<(BBATCH*16*L2W + 255)/256, 256, 0, stream>>>(chnk, seq);
    k_ssm<<<16, 128, 0, stream>>>(seq, Amat, Bmat, Cmat, hbuf);

    for (int l = 0; l < 2; l++) {
        k_attnf<<<LSEQ*NHEAD, 128, 0, stream>>>(hbuf, qkv_w + l*768, qkv_b + l*48, obuf);
        k_post<<<(BBATCH*LSEQ + 255)/256, 256, 0, stream>>>(hbuf, obuf,
            proj_w + l*256, proj_b + l*16,
            ff1_w + l*1024, ff1_b + l*64,
            ff2_w + l*1024, ff2_b + l*16,
            ln1_g + l*16, ln1_b + l*16,
            ln2_g + l*16, ln2_b + l*16,
            hbuf, out, (l == 1) ? 1 : 0);
    }
}

// Round 4
// 213.822 us; speedup vs baseline: 1.9419x; 1.1988x over previous
//
#include <hip/hip_runtime.h>
#include <hip/hip_bf16.h>
#include <math.h>

// Problem dims
#define BBATCH 128
#define NCHAN  22
#define TLEN   1000
#define F1C    8
#define F2C    16
#define L1W    31
#define L2W    38
#define LSEQ   69
#define EDIM   16
#define NHEAD  8
#define FFDIM  64

// const block offsets (floats within ws)
#define C_SA   0
#define C_BA   16
#define C_BC2  32
#define C_W2T  48                       // [(h*30+k)*16 + c2], s5-folded
#define C_W1P  (48 + 16*22*30)          // padded 8 x 128 spec1 filters
#define C_QWC  (C_W1P + 8*128)          // 48x16: qkv_w(layer0) @ Cm
#define C_TOTAL (C_QWC + 768)

// ws layout (floats)
#define OFF_CONST 0
#define OFF_CHNK  16384
#define OFF_SEQ   (OFF_CHNK + 81920)
#define OFF_STB   (OFF_SEQ + 141312)
#define OFF_HBUF  (OFF_STB + 141312)
#define OFF_OBUF  (OFF_HBUF + 141312)

// broadcast-from-lane-i within 16-lane groups (wave64-safe)
#define SWZ(v, imm) __int_as_float(__builtin_amdgcn_ds_swizzle(__float_as_int(v), imm))
#define MV16(dst, sv, W) do { \
    float p0=SWZ(sv,0x010)*W[0],  p1=SWZ(sv,0x030)*W[1],  \
          p2=SWZ(sv,0x050)*W[2],  p3=SWZ(sv,0x070)*W[3],  \
          p4=SWZ(sv,0x090)*W[4],  p5=SWZ(sv,0x0B0)*W[5],  \
          p6=SWZ(sv,0x0D0)*W[6],  p7=SWZ(sv,0x0F0)*W[7],  \
          p8=SWZ(sv,0x110)*W[8],  p9=SWZ(sv,0x130)*W[9],  \
          p10=SWZ(sv,0x150)*W[10],p11=SWZ(sv,0x170)*W[11],\
          p12=SWZ(sv,0x190)*W[12],p13=SWZ(sv,0x1B0)*W[13],\
          p14=SWZ(sv,0x1D0)*W[14],p15=SWZ(sv,0x1F0)*W[15];\
    dst = (((p0+p1)+(p2+p3))+((p4+p5)+(p6+p7))) + (((p8+p9)+(p10+p11))+((p12+p13)+(p14+p15))); \
} while(0)

// ---------------- setup: fold BN + compose weights ----------------
__global__ void k_setup(const float* __restrict__ wsp1a, const float* __restrict__ b_spec1,
                        const float* __restrict__ g_bn1, const float* __restrict__ b_bn1,
                        const float* __restrict__ g_bn3, const float* __restrict__ b_bn3,
                        const float* __restrict__ w_spec2, const float* __restrict__ b_spec2,
                        const float* __restrict__ g_bn2, const float* __restrict__ b_bn2,
                        const float* __restrict__ w_sp2, const float* __restrict__ b_sp2,
                        const float* __restrict__ g_bn5, const float* __restrict__ b_bn5,
                        const float* __restrict__ w_spec1, const float* __restrict__ qkvw0,
                        const float* __restrict__ Cmat,
                        float* __restrict__ consts)
{
    int tid = threadIdx.x;
    float rbn = rsqrtf(1.0f + 1e-5f);
    if (tid < 16) {
        int c2 = tid, c1 = c2 >> 1;
        float wsum = 0.f;
        for (int h = 0; h < NCHAN; h++) wsum += wsp1a[c2*NCHAN + h];
        float s1b = g_bn1[c1] * rbn;
        float s3  = g_bn3[c2] * rbn;
        float C1  = (s1b * b_spec1[c1] + b_bn1[c1]) * wsum;
        consts[C_SA + c2] = s3 * s1b;
        consts[C_BA + c2] = s3 * C1 + b_bn3[c2];
        float s5 = g_bn5[c2] * rbn;
        float acc = b_sp2[c2];
        for (int cc = 0; cc < F1C; cc++) {
            float s2b = g_bn2[cc] * rbn;
            float cb  = s2b * b_spec2[cc] + b_bn2[cc];
            float wsh = 0.f;
            for (int h = 0; h < NCHAN; h++) wsh += w_sp2[(c2*F1C + cc)*NCHAN + h];
            acc += wsh * cb;
        }
        consts[C_BC2 + c2] = s5 * acc + b_bn5[c2];
    }
    // transposed branch-2 filter: W2T[(h*30+k)*16 + c2]
    for (int idx = tid; idx < 16*22*30; idx += 256) {
        int c2 = idx & 15;
        int hk = idx >> 4;
        int h = hk / 30, k = hk % 30;
        float s5 = g_bn5[c2] * rbn;
        float s = 0.f;
        for (int cc = 0; cc < F1C; cc++)
            s += w_sp2[(c2*F1C + cc)*NCHAN + h] * (g_bn2[cc] * rbn) * w_spec2[cc*30 + k];
        consts[C_W2T + idx] = s5 * s;
    }
    // padded spec1 filters: 8 x 128, taps 125..127 = 0
    for (int idx = tid; idx < 8*128; idx += 256) {
        int c1 = idx >> 7, k = idx & 127;
        consts[C_W1P + idx] = (k < 125) ? w_spec1[c1*125 + k] : 0.f;
    }
    // folded layer-1 qkv weight: qwC[o][i] = sum_j qkvw0[o][j] * Cm[j][i]
    for (int idx = tid; idx < 768; idx += 256) {
        int o = idx >> 4, i = idx & 15;
        float s = 0.f;
        for (int jj = 0; jj < 16; jj++) s += qkvw0[o*16 + jj] * Cmat[jj*16 + i];
        consts[C_QWC + idx] = s;
    }
}

// ---------------- branch 1 fully fused ----------------
#define P1 388
#define P2 260
#define PW 132
__global__ void k_b1f(const float* __restrict__ x, const float* __restrict__ wsp1a,
                      const float* __restrict__ consts,
                      const float* __restrict__ w_sp1b, const float* __restrict__ b_sp1b,
                      const float* __restrict__ g_bn4, const float* __restrict__ b_bn4,
                      float* __restrict__ seq)
{
    __shared__ __align__(16) float mrow[16*P1];
    __shared__ __align__(16) float econv[16*P2];
    __shared__ float wlds[8*PW];
    int bid = blockIdx.x;
    int q = bid & 3, b = bid >> 2;
    int tid = threadIdx.x;
    int t0 = q * 256;
    int NT = (q == 3) ? 224 : 256;
    int NCOL = NT + 124;

    for (int j = tid; j < NCOL; j += 256) {
        int t = t0 - 62 + j;
        float xv[NCHAN];
#pragma unroll
        for (int h = 0; h < NCHAN; h++)
            xv[h] = ((unsigned)t < 1000u) ? x[(b*NCHAN + h)*TLEN + t] : 0.f;
#pragma unroll
        for (int c2 = 0; c2 < 16; c2++) {
            float s = 0.f;
#pragma unroll
            for (int h = 0; h < NCHAN; h++) s += wsp1a[c2*NCHAN + h] * xv[h];
            mrow[c2*P1 + j] = s;
        }
    }
    for (int j = NCOL + tid; j < P1; j += 256) {
#pragma unroll
        for (int c2 = 0; c2 < 16; c2++) mrow[c2*P1 + j] = 0.f;
    }
    for (int i = tid; i < 1024; i += 256)
        wlds[(i >> 7)*PW + (i & 127)] = consts[C_W1P + i];
    __syncthreads();

    {
        int c2 = tid & 15, seg = tid >> 4, c1 = c2 >> 1;
        if (seg < (NT >> 4)) {
            int u0 = seg * 16;
            const float* mr = &mrow[c2*P1 + u0];
            float sa = consts[C_SA + c2], ba = consts[C_BA + c2];
            float v[20];
            {
                float4 a0 = *(const float4*)&mr[0];
                float4 a1 = *(const float4*)&mr[4];
                float4 a2 = *(const float4*)&mr[8];
                float4 a3 = *(const float4*)&mr[12];
                float4 a4 = *(const float4*)&mr[16];
                v[0]=a0.x; v[1]=a0.y; v[2]=a0.z; v[3]=a0.w;
                v[4]=a1.x; v[5]=a1.y; v[6]=a1.z; v[7]=a1.w;
                v[8]=a2.x; v[9]=a2.y; v[10]=a2.z; v[11]=a2.w;
                v[12]=a3.x; v[13]=a3.y; v[14]=a3.z; v[15]=a3.w;
                v[16]=a4.x; v[17]=a4.y; v[18]=a4.z; v[19]=a4.w;
            }
            float acc[16];
#pragma unroll
            for (int u = 0; u < 16; u++) acc[u] = 0.f;
#pragma unroll
            for (int k0 = 0; k0 < 128; k0 += 4) {
                float w0 = wlds[c1*PW + k0 + 0];
                float w1 = wlds[c1*PW + k0 + 1];
                float w2 = wlds[c1*PW + k0 + 2];
                float w3 = wlds[c1*PW + k0 + 3];
#pragma unroll
                for (int u = 0; u < 16; u++) {
                    acc[u] += w0 * v[u+0];
                    acc[u] += w1 * v[u+1];
                    acc[u] += w2 * v[u+2];
                    acc[u] += w3 * v[u+3];
                }
                if (k0 < 124) {
#pragma unroll
                    for (int i = 0; i < 16; i++) v[i] = v[i+4];
                    float4 nv = *(const float4*)&mr[k0 + 20];
                    v[16]=nv.x; v[17]=nv.y; v[18]=nv.z; v[19]=nv.w;
                }
            }
            float e[16];
#pragma unroll
            for (int u = 0; u < 16; u++) {
                float a = sa * acc[u] + ba;
                e[u] = (a > 0.f) ? a : (expf(a) - 1.f);
            }
            float* ec = &econv[c2*P2 + u0];
#pragma unroll
            for (int i = 0; i < 4; i++)
                *(float4*)&ec[4*i] = make_float4(e[4*i], e[4*i+1], e[4*i+2], e[4*i+3]);
        }
    }
    __syncthreads();

    if (tid < NT) {
        int u = tid;
        float rbn = rsqrtf(1.0f + 1e-5f);
        float hv[16];
#pragma unroll
        for (int c = 0; c < 16; c++) hv[c] = econv[c*P2 + u];
        float p[16];
#pragma unroll
        for (int c = 0; c < 16; c++) {
            float s = 0.f;
#pragma unroll
            for (int j = 0; j < 16; j++) s += w_sp1b[c*16 + j] * hv[j];
            float sc = g_bn4[c] * rbn;
            float a = sc * (s + b_sp1b[c]) + b_bn4[c];
            float g = (a > 0.f) ? a : (expf(a) - 1.f);
            g += __shfl_xor(g, 1, 64);
            g += __shfl_xor(g, 2, 64);
            g += __shfl_xor(g, 4, 64);
            g += __shfl_xor(g, 8, 64);
            g += __shfl_xor(g, 16, 64);
            p[c] = g;
        }
        if ((u & 31) == 0) {
            int w = 8*q + (u >> 5);
            float* sp = &seq[(b*LSEQ + w)*16];
#pragma unroll
            for (int i = 0; i < 4; i++)
                *(float4*)&sp[4*i] = make_float4(p[4*i]*(1.f/32.f), p[4*i+1]*(1.f/32.f),
                                                 p[4*i+2]*(1.f/32.f), p[4*i+3]*(1.f/32.f));
        }
    }
}

// ---------------- branch 2: fused conv + square + 25-chunk sums ----------
__global__ void k_b2conv(const float* __restrict__ x, const float* __restrict__ consts,
                         float* __restrict__ chnk)
{
    __shared__ float sx[NCHAN * 280];
    __shared__ float sq[16 * 252];
    int bid = blockIdx.x;
    int tq = bid & 3, b = bid >> 2;
    int t0 = tq * 250;
    int tid = threadIdx.x;

    for (int idx = tid; idx < NCHAN*280; idx += 256) {
        int h = idx / 280, i = idx - h*280;
        int t = t0 - 14 + i;
        sx[idx] = ((unsigned)t < 1000u) ? x[(b*NCHAN + h)*TLEN + t] : 0.f;
    }
    __syncthreads();

    if (tid < 250) {
        float acc[16];
#pragma unroll
        for (int c = 0; c < 16; c++) acc[c] = 0.f;
        for (int h = 0; h < NCHAN; h++) {
            const float* sp = &sx[h*280 + tid];
            const float* wp = consts + C_W2T + h*480;
#pragma unroll
            for (int k = 0; k < 30; k++) {
                float vk = sp[k];
#pragma unroll
                for (int c2 = 0; c2 < 16; c2++)
                    acc[c2] += wp[k*16 + c2] * vk;
            }
        }
#pragma unroll
        for (int c2 = 0; c2 < 16; c2++) {
            float a = acc[c2] + consts[C_BC2 + c2];
            sq[c2*252 + tid] = a * a;
        }
    }
    __syncthreads();

    if (tid < 160) {
        int c2 = tid / 10, ch = tid % 10;
        const float* s = &sq[c2*252 + ch*25];
        float acc = 0.f;
#pragma unroll
        for (int i = 0; i < 25; i++) acc += s[i];
        chnk[(b*16 + c2)*40 + tq*10 + ch] = acc;
    }
}

// ---------------- SSM scan: pool2-log fused, u-precompute, tree matvec ----
__global__ void k_ssm(const float* __restrict__ seq, const float* __restrict__ chnk,
                      const float* __restrict__ Amat, const float* __restrict__ Bmat,
                      float* __restrict__ stbuf)
{
    int tid = threadIdx.x;          // 64
    int j = tid & 15;
    int b = blockIdx.x * 4 + (tid >> 4);

    float Acol[16], Brow[16];
#pragma unroll
    for (int i = 0; i < 16; i++) {
        Acol[i] = Amat[i*16 + j];
        Brow[i] = Bmat[j*16 + i];
    }

    float xv[LSEQ];
#pragma unroll
    for (int l = 0; l < 31; l++) xv[l] = seq[(b*LSEQ + l)*16 + j];
    {
        float cp[40];
        const float4* cpp = (const float4*)(chnk + (b*16 + j)*40);
#pragma unroll
        for (int i = 0; i < 10; i++) {
            float4 v = cpp[i];
            cp[4*i]=v.x; cp[4*i+1]=v.y; cp[4*i+2]=v.z; cp[4*i+3]=v.w;
        }
#pragma unroll
        for (int w = 0; w < 38; w++) {
            float m = (cp[w] + cp[w+1] + cp[w+2]) * (1.f/75.f);
            xv[31 + w] = logf(fmaxf(m, 1e-6f));
        }
    }

#pragma unroll
    for (int l = 0; l < LSEQ; l++) {
        float u;
        MV16(u, xv[l], Brow);
        xv[l] = u;
    }

    float* sb = stbuf + b*LSEQ*16 + j;
    float st = 0.f;
#pragma unroll
    for (int l = 0; l < LSEQ; l++) {
        float nv;
        MV16(nv, st, Acol);
        st = nv + xv[l];
        sb[l*16] = st;
    }
}

// ---------------- attention (qkv fused in) over batch axis ----------------
__global__ void k_attnf(const float* __restrict__ h, const float* __restrict__ qw,
                        const float* __restrict__ qb, float* __restrict__ obuf)
{
    int n = blockIdx.x >> 3, hh = blockIdx.x & 7;
    __shared__ float kv[128][4];
    int s = threadIdx.x;            // 128 threads
    const float* hr = h + (s*LSEQ + n)*16;
    float hv[16];
#pragma unroll
    for (int i = 0; i < 4; i++) {
        float4 a = *(const float4*)&hr[4*i];
        hv[4*i]=a.x; hv[4*i+1]=a.y; hv[4*i+2]=a.z; hv[4*i+3]=a.w;
    }
    int r0 = 2*hh;
    float pr[6];
#pragma unroll
    for (int d = 0; d < 6; d++) {
        int row = (d >> 1)*16 + r0 + (d & 1);
        float sum = qb[row];
#pragma unroll
        for (int c = 0; c < 16; c++) sum += qw[row*16 + c] * hv[c];
        pr[d] = sum;
    }
    const float RS2 = 0.70710678118654752f;
    float q0 = pr[0]*RS2, q1 = pr[1]*RS2;
    *(float4*)&kv[s][0] = make_float4(pr[2], pr[3], pr[4], pr[5]);
    __syncthreads();
    float m = -1e30f, sum = 0.f, o0 = 0.f, o1 = 0.f;
    for (int t = 0; t < 128; t++) {
        float sc = q0*kv[t][0] + q1*kv[t][1];
        float nm = fmaxf(m, sc);
        float cor = expf(m - nm);
        float e = expf(sc - nm);
        sum = sum*cor + e;
        o0 = o0*cor + e*kv[t][2];
        o1 = o1*cor + e*kv[t][3];
        m = nm;
    }
    float inv = 1.f / sum;
    obuf[(s*LSEQ + n)*16 + r0 + 0] = o0 * inv;
    obuf[(s*LSEQ + n)*16 + r0 + 1] = o1 * inv;
}

// proj + residual + LN1 + FF + residual + LN2
__global__ void k_post(const float* __restrict__ hin, const float* __restrict__ obuf,
                       const float* __restrict__ pw, const float* __restrict__ pb,
                       const float* __restrict__ f1w, const float* __restrict__ f1b,
                       const float* __restrict__ f2w, const float* __restrict__ f2b,
                       const float* __restrict__ lg1, const float* __restrict__ lb1,
                       const float* __restrict__ lg2, const float* __restrict__ lb2,
                       const float* __restrict__ Cmat, int applyC,
                       float* __restrict__ hout, float* __restrict__ fout, int writeFinal)
{
    __shared__ float pwl[256], f1wl[1024], f2wl[1024], Cml[256];
    __shared__ float pbl[16], f1bl[64], f2bl[16], g1l[16], b1l[16], g2l[16], b2l[16];
    int tid = threadIdx.x;
    pwl[tid] = pw[tid];
    Cml[tid] = Cmat[tid];
    for (int i = tid; i < 1024; i += 256) { f1wl[i] = f1w[i]; f2wl[i] = f2w[i]; }
    if (tid < 16) {
        pbl[tid] = pb[tid]; f2bl[tid] = f2b[tid];
        g1l[tid] = lg1[tid]; b1l[tid] = lb1[tid];
        g2l[tid] = lg2[tid]; b2l[tid] = lb2[tid];
    }
    if (tid < 64) f1bl[tid] = f1b[tid];
    __syncthreads();
    int r = blockIdx.x * 256 + tid;
    if (r >= BBATCH * LSEQ) return;
    float rv[16], ov[16];
    const float4* hp = (const float4*)(hin + r*16);
    const float4* op = (const float4*)(obuf + r*16);
#pragma unroll
    for (int i = 0; i < 4; i++) {
        float4 a = hp[i];
        rv[4*i] = a.x; rv[4*i+1] = a.y; rv[4*i+2] = a.z; rv[4*i+3] = a.w;
        float4 bq = op[i];
        ov[4*i] = bq.x; ov[4*i+1] = bq.y; ov[4*i+2] = bq.z; ov[4*i+3] = bq.w;
    }
    float hv[16];
    if (applyC) {
#pragma unroll
        for (int c = 0; c < 16; c++) {
            float s = 0.f;
#pragma unroll
            for (int i = 0; i < 16; i++) s += rv[i] * Cml[c*16 + i];
            hv[c] = s;
        }
    } else {
#pragma unroll
        for (int c = 0; c < 16; c++) hv[c] = rv[c];
    }
    float h1[16];
#pragma unroll
    for (int c = 0; c < 16; c++) {
        float p = pbl[c];
#pragma unroll
        for (int j = 0; j < 16; j++) p += pwl[c*16 + j] * ov[j];
        h1[c] = hv[c] + p;
    }
    float mn = 0.f;
#pragma unroll
    for (int c = 0; c < 16; c++) mn += h1[c];
    mn *= (1.f/16.f);
    float var = 0.f;
#pragma unroll
    for (int c = 0; c < 16; c++) { float d = h1[c] - mn; var += d*d; }
    var *= (1.f/16.f);
    float rs = rsqrtf(var + 1e-5f);
    float y[16];
#pragma unroll
    for (int c = 0; c < 16; c++) y[c] = (h1[c] - mn)*rs*g1l[c] + b1l[c];
    float t2[16];
#pragma unroll
    for (int c = 0; c < 16; c++) t2[c] = f2bl[c];
    for (int u = 0; u < 64; u++) {
        float s = f1bl[u];
#pragma unroll
        for (int c = 0; c < 16; c++) s += f1wl[u*16 + c] * y[c];
        s = fmaxf(s, 0.f);
#pragma unroll
        for (int c = 0; c < 16; c++) t2[c] += f2wl[c*64 + u] * s;
    }
    float h2[16];
#pragma unroll
    for (int c = 0; c < 16; c++) h2[c] = y[c] + t2[c];
    mn = 0.f;
#pragma unroll
    for (int c = 0; c < 16; c++) mn += h2[c];
    mn *= (1.f/16.f);
    var = 0.f;
#pragma unroll
    for (int c = 0; c < 16; c++) { float d = h2[c] - mn; var += d*d; }
    var *= (1.f/16.f);
    rs = rsqrtf(var + 1e-5f);
    float z[16];
#pragma unroll
    for (int c = 0; c < 16; c++) z[c] = (h2[c] - mn)*rs*g2l[c] + b2l[c];
#pragma unroll
    for (int c = 0; c < 16; c++) hout[r*16 + c] = z[c];
    if (writeFinal) {
        int b = r / LSEQ, n = r % LSEQ;
#pragma unroll
        for (int c = 0; c < 16; c++) fout[(b*16 + c)*LSEQ + n] = z[c];
    }
}

extern "C" void kernel_launch(void* const* d_in, const int* in_sizes, int n_in,
                              void* d_out, int out_size, void* d_ws, size_t ws_size,
                              hipStream_t stream)
{
    const float* x       = (const float*)d_in[0];
    const float* w_spec1 = (const float*)d_in[1];
    const float* b_spec1 = (const float*)d_in[2];
    const float* w_spec2 = (const float*)d_in[3];
    const float* b_spec2 = (const float*)d_in[4];
    const float* g_bn1   = (const float*)d_in[5];
    const float* b_bn1   = (const float*)d_in[6];
    const float* g_bn2   = (const float*)d_in[7];
    const float* b_bn2   = (const float*)d_in[8];
    const float* w_sp1a  = (const float*)d_in[9];
    const float* g_bn3   = (const float*)d_in[10];
    const float* b_bn3   = (const float*)d_in[11];
    const float* w_sp1b  = (const float*)d_in[12];
    const float* b_sp1b  = (const float*)d_in[13];
    const float* g_bn4   = (const float*)d_in[14];
    const float* b_bn4   = (const float*)d_in[15];
    const float* w_sp2   = (const float*)d_in[16];
    const float* b_sp2   = (const float*)d_in[17];
    const float* g_bn5   = (const float*)d_in[18];
    const float* b_bn5   = (const float*)d_in[19];
    const float* Amat    = (const float*)d_in[20];
    const float* Bmat    = (const float*)d_in[21];
    const float* Cmat    = (const float*)d_in[22];
    const float* qkv_w   = (const float*)d_in[23];
    const float* qkv_b   = (const float*)d_in[24];
    const float* proj_w  = (const float*)d_in[25];
    const float* proj_b  = (const float*)d_in[26];
    const float* ff1_w   = (const float*)d_in[27];
    const float* ff1_b   = (const float*)d_in[28];
    const float* ff2_w   = (const float*)d_in[29];
    const float* ff2_b   = (const float*)d_in[30];
    const float* ln1_g   = (const float*)d_in[31];
    const float* ln1_b   = (const float*)d_in[32];
    const float* ln2_g   = (const float*)d_in[33];
    const float* ln2_b   = (const float*)d_in[34];

    float* ws  = (float*)d_ws;
    float* out = (float*)d_out;

    float* consts = ws + OFF_CONST;
    float* chnk   = ws + OFF_CHNK;
    float* seq    = ws + OFF_SEQ;
    float* stbuf  = ws + OFF_STB;
    float* hbuf   = ws + OFF_HBUF;
    float* obuf   = ws + OFF_OBUF;

    k_setup<<<1, 256, 0, stream>>>(w_sp1a, b_spec1, g_bn1, b_bn1, g_bn3, b_bn3,
                                   w_spec2, b_spec2, g_bn2, b_bn2,
                                   w_sp2, b_sp2, g_bn5, b_bn5, w_spec1,
                                   qkv_w, Cmat, consts);
    k_b1f<<<BBATCH*4, 256, 0, stream>>>(x, w_sp1a, consts, w_sp1b, b_sp1b, g_bn4, b_bn4, seq);
    k_b2conv<<<BBATCH*4, 256, 0, stream>>>(x, consts, chnk);
    k_ssm<<<BBATCH/4, 64, 0, stream>>>(seq, chnk, Amat, Bmat, stbuf);

    // layer 1: attn reads raw states with C folded into qkv weights;
    // post applies C on the fly for the residual path.
    k_attnf<<<LSEQ*NHEAD, 128, 0, stream>>>(stbuf, consts + C_QWC, qkv_b, obuf);
    k_post<<<(BBATCH*LSEQ + 255)/256, 256, 0, stream>>>(stbuf, obuf,
        proj_w, proj_b, ff1_w, ff1_b, ff2_w, ff2_b,
        ln1_g, ln1_b, ln2_g, ln2_b, Cmat, 1, hbuf, out, 0);

    // layer 2
    k_attnf<<<LSEQ*NHEAD, 128, 0, stream>>>(hbuf, qkv_w + 768, qkv_b + 48, obuf);
    k_post<<<(BBATCH*LSEQ + 255)/256, 256, 0, stream>>>(hbuf, obuf,
        proj_w + 256, proj_b + 16, ff1_w + 1024, ff1_b + 64,
        ff2_w + 1024, ff2_b + 16, ln1_g + 16, ln1_b + 16, ln2_g + 16, ln2_b + 16,
        Cmat, 0, hbuf, out, 1);
}